// Round 10
// baseline (745.437 us; speedup 1.0000x reference)
//
#include <hip/hip_runtime.h>
#include <hip/hip_fp16.h>

typedef __half f16;
typedef _Float16 half8 __attribute__((ext_vector_type(8)));
typedef float floatx4 __attribute__((ext_vector_type(4)));

#define NN   100000   // nodes
#define NE   1600000  // edges
#define CIN  256
#define CH   128
#define COUT 64
#define NB   64

#define NBUK 128      // CSR buckets
#define NPB  782      // nodes per bucket (128*782 = 100096 >= NN)
#define BCAP 32       // LDS bin slots per bucket (k_bin)
#define CAPB 20480    // staging capacity per bucket
#define G1   512      // k_bin blocks
#define EPB  3125     // edges per k_bin block
#define CSZ  15104    // k_csr LDS csr entries

// ---------------- diagnostics ----------------
__global__ void k_sentinel(float* __restrict__ out, int n, float val) {
    int i = blockIdx.x * 256 + threadIdx.x;
    if (i < n) out[i] = val;
}

// ---------------- init ----------------
__global__ void k_init(float* __restrict__ pool, float* __restrict__ cnt,
                       int* __restrict__ gcur) {
    int i = blockIdx.x * 256 + threadIdx.x;
    if (i < NB * CH) pool[i] = 0.0f;
    if (i < NB) cnt[i] = 0.0f;
    if (i < NBUK) gcur[i] = i * CAPB;
}

// ---------------- phase 1: bin edges by dst bucket ----------------
__global__ __launch_bounds__(256) void k_bin(const int* __restrict__ src,
                                             const int* __restrict__ dst,
                                             int* __restrict__ gcur,
                                             int* __restrict__ stage) {
    __shared__ int bins[NBUK][BCAP];
    __shared__ int bcnt[NBUK];
    __shared__ int fcnt[NBUK];
    __shared__ int fbase[NBUK];
    const int tid = threadIdx.x;
    if (tid < NBUK) bcnt[tid] = 0;
    __syncthreads();
    const int e0 = blockIdx.x * EPB;
    const int e1 = (e0 + EPB < NE) ? e0 + EPB : NE;
    for (int base = e0; base < e1; base += 256) {
        int e = base + tid;
        if (e < e1) {
            int s = src[e], d = dst[e];
            int bk = d / NPB;
            int pk = ((d - bk * NPB) << 17) | s;
            int pos = atomicAdd(&bcnt[bk], 1);
            if (pos < BCAP) {
                bins[bk][pos] = pk;
            } else {
                int gp = atomicAdd(&gcur[bk], 1);
                if (gp < (bk + 1) * CAPB) stage[gp] = pk;
            }
        }
        __syncthreads();
        if (tid < NBUK) {
            int stored = bcnt[tid]; if (stored > BCAP) stored = BCAP;
            int nf = stored & ~15;
            fcnt[tid] = nf;
            if (nf) fbase[tid] = atomicAdd(&gcur[tid], nf);
        }
        __syncthreads();
#pragma unroll
        for (int pass = 0; pass < NBUK / 16; ++pass) {
            int b = pass * 16 + (tid >> 4);
            int sl = tid & 15;
            int nf = fcnt[b];
            int fb = fbase[b];
            for (int k = sl; k < nf; k += 16)
                if (fb + k < (b + 1) * CAPB) stage[fb + k] = bins[b][k];
        }
        __syncthreads();
        if (tid < NBUK) {
            int stored = bcnt[tid]; if (stored > BCAP) stored = BCAP;
            int nf = fcnt[tid];
            for (int k = nf; k < stored; ++k) bins[tid][k - nf] = bins[tid][k];
            bcnt[tid] = stored - nf;
        }
        __syncthreads();
    }
    if (tid < NBUK) {
        int stored = bcnt[tid];
        fcnt[tid] = stored;
        if (stored) fbase[tid] = atomicAdd(&gcur[tid], stored);
    }
    __syncthreads();
#pragma unroll
    for (int pass = 0; pass < NBUK / 16; ++pass) {
        int b = pass * 16 + (tid >> 4);
        int sl = tid & 15;
        int nf = fcnt[b];
        int fb = fbase[b];
        for (int k = sl; k < nf; k += 16)
            if (fb + k < (b + 1) * CAPB) stage[fb + k] = bins[b][k];
    }
}

// ---------------- phase 1b: scan bucket totals ----------------
__global__ void k_gtot(const int* __restrict__ gcur, int* __restrict__ barr,
                       int* __restrict__ rowptr) {
    int lane = threadIdx.x;   // 64 threads
    int carry = 0;
    for (int c0 = 0; c0 < NBUK; c0 += 64) {
        int idx = c0 + lane;
        int orig = gcur[idx] - idx * CAPB;
        int v = orig;
#pragma unroll
        for (int off = 1; off < 64; off <<= 1) {
            int t = __shfl_up(v, off);
            if (lane >= off) v += t;
        }
        barr[idx] = v - orig + carry;
        carry += __shfl(v, 63);
    }
    if (lane == 0) rowptr[NN] = NE;
}

// ---------------- phase 2: per-bucket CSR + rowptr + dinv ----------------
__global__ __launch_bounds__(256) void k_csr(const int* __restrict__ gcur,
                                             const int* __restrict__ barr,
                                             const int* __restrict__ stage,
                                             int* __restrict__ rowptr,
                                             int* __restrict__ csr,
                                             float* __restrict__ dinv) {
    __shared__ int hist[NPB];
    __shared__ int lcsr[CSZ];
    const int b = blockIdx.x, tid = threadIdx.x;
    const int nbase = b * NPB;
    const int nloc = (NPB < NN - nbase) ? NPB : NN - nbase;
    const int count = gcur[b] - b * CAPB;
    const int gbase = barr[b];
    const int sb = b * CAPB;
    for (int i = tid; i < NPB; i += 256) hist[i] = 0;
    __syncthreads();
    for (int i = tid; i < count; i += 256)
        atomicAdd(&hist[stage[sb + i] >> 17], 1);
    __syncthreads();
    for (int dl = tid; dl < nloc; dl += 256)
        dinv[nbase + dl] = rsqrtf((float)hist[dl] + 1.0f);
    __syncthreads();
    if (tid < 64) {
        int carry = 0;
        for (int c0 = 0; c0 < NPB; c0 += 64) {
            int idx = c0 + tid;
            int orig = (idx < NPB) ? hist[idx] : 0;
            int v = orig;
#pragma unroll
            for (int off = 1; off < 64; off <<= 1) {
                int t = __shfl_up(v, off);
                if (tid >= off) v += t;
            }
            if (idx < NPB) hist[idx] = v - orig + carry;
            carry += __shfl(v, 63);
        }
    }
    __syncthreads();
    for (int dl = tid; dl < nloc; dl += 256)
        rowptr[nbase + dl] = gbase + hist[dl];
    __syncthreads();
    const bool fits = (count <= CSZ);
    for (int i = tid; i < count; i += 256) {
        int pk = stage[sb + i];
        int dl = pk >> 17, s = pk & 0x1FFFF;
        int pos = atomicAdd(&hist[dl], 1);
        if (fits) lcsr[pos] = s;
        else csr[gbase + pos] = s;
    }
    __syncthreads();
    if (fits)
        for (int i = tid; i < count; i += 256) csr[gbase + i] = lcsr[i];
}

// ---------------- weight -> f16 fragment-major conversion ----------------
__global__ __launch_bounds__(256) void k_wconv(
        const float* __restrict__ W0, const float* __restrict__ Wres,
        const float* __restrict__ W1, const float* __restrict__ W2,
        const float* __restrict__ Wl0, const float* __restrict__ Wl1,
        half8* __restrict__ F0, half8* __restrict__ Fres,
        half8* __restrict__ F1, half8* __restrict__ F2,
        half8* __restrict__ Fl0, half8* __restrict__ Fl1) {
    int f = blockIdx.x * 256 + threadIdx.x;
    const float* W; half8* F; int M, base;
    if      (f <  4096) { W = W0;   F = F0;   M = 128; base = 0; }
    else if (f <  8192) { W = Wres; F = Fres; M = 128; base = 4096; }
    else if (f < 10240) { W = W1;   F = F1;   M = 128; base = 8192; }
    else if (f < 12288) { W = W2;   F = F2;   M = 128; base = 10240; }
    else if (f < 14336) { W = Wl0;  F = Fl0;  M = 128; base = 12288; }
    else if (f < 15360) { W = Wl1;  F = Fl1;  M = 64;  base = 14336; }
    else return;
    int fl = f - base;
    int lane = fl & 63, fm = lane & 15, g = lane >> 4;
    int rest = fl >> 6;
    int nt = M / 16;
    int t = rest % nt, kt = rest / nt;
    half8 v;
#pragma unroll
    for (int j = 0; j < 8; ++j)
        v[j] = (_Float16)W[(size_t)(kt * 32 + g * 8 + j) * M + t * 16 + fm];
    F[fl] = v;
}

// ---------------- MFMA GEMM, software-pipelined A staging ----------------
// C[N,M] = A[N,K] @ W[K,M]; 256 thr, 64 rows x M cols; B-frags from global (L2).
// Double-buffered LDS A-tiles: tile kt+1's global loads are issued before the
// MFMAs of tile kt; converted+stored after; one barrier per tile.
template <int M, int EPI, bool AF32>
__global__ __launch_bounds__(256) void k_mfma(const void* __restrict__ Av,
                                              const half8* __restrict__ WF,
                                              const half8* __restrict__ WFb,
                                              const float* __restrict__ bias,
                                              const float* __restrict__ dinv,
                                              f16* __restrict__ lout,
                                              f16* __restrict__ rout,
                                              float* __restrict__ fout,
                                              int K) {
    constexpr int KC = 32, APAD = 40;
    constexpr int NT = M / 16;
    __shared__ _Float16 Al[2][64 * APAD];
    const int tid = threadIdx.x;
    const int wave = tid >> 6, lane = tid & 63;
    const int fm = lane & 15, g = lane >> 4;
    const int rb = blockIdx.x * 64;
    const int KT = K / KC;

    floatx4 acc[NT];
#pragma unroll
    for (int t = 0; t < NT; ++t)
#pragma unroll
        for (int r = 0; r < 4; ++r) acc[t][r] = 0.0f;

    const int arow = tid >> 2;            // 0..63
    const int koff = (tid & 3) * 8;
    const int grow = rb + arow;
    const bool rok = (grow < NN);

    float4 sv0, sv1;                      // AF32 staging regs
    half8  sh;                            // f16 staging regs

    // ---- prologue: load + store tile 0 ----
    if (rok) {
        if (AF32) {
            const float* ap = (const float*)Av + (size_t)grow * K + koff;
            sv0 = *(const float4*)ap;
            sv1 = *(const float4*)(ap + 4);
        } else {
            sh = *(const half8*)((const _Float16*)Av + (size_t)grow * K + koff);
        }
    }
    {
        half8 av;
        if (rok) {
            if (AF32) {
                av[0] = (_Float16)sv0.x; av[1] = (_Float16)sv0.y;
                av[2] = (_Float16)sv0.z; av[3] = (_Float16)sv0.w;
                av[4] = (_Float16)sv1.x; av[5] = (_Float16)sv1.y;
                av[6] = (_Float16)sv1.z; av[7] = (_Float16)sv1.w;
            } else av = sh;
        } else {
#pragma unroll
            for (int i = 0; i < 8; ++i) av[i] = (_Float16)0.0f;
        }
        *(half8*)&Al[0][arow * APAD + koff] = av;
    }

    for (int kt = 0; kt < KT; ++kt) {
        __syncthreads();                  // tile kt staged for all waves
        const bool pf = (kt + 1 < KT);
        if (pf && rok) {                  // issue tile kt+1 loads NOW
            int k0 = (kt + 1) * KC;
            if (AF32) {
                const float* ap = (const float*)Av + (size_t)grow * K + k0 + koff;
                sv0 = *(const float4*)ap;
                sv1 = *(const float4*)(ap + 4);
            } else {
                sh = *(const half8*)((const _Float16*)Av + (size_t)grow * K + k0 + koff);
            }
        }
        half8 afrag = *(const half8*)&Al[kt & 1][(wave * 16 + fm) * APAD + g * 8];
#pragma unroll
        for (int t = 0; t < NT; ++t) {
            half8 bfrag;
            if (EPI == 0) {
                bfrag = (t < 8) ? WF[((size_t)kt * 8 + t) * 64 + lane]
                                : WFb[((size_t)kt * 8 + (t - 8)) * 64 + lane];
            } else {
                bfrag = WF[((size_t)kt * NT + t) * 64 + lane];
            }
            acc[t] = __builtin_amdgcn_mfma_f32_16x16x32_f16(afrag, bfrag, acc[t], 0, 0, 0);
        }
        if (pf) {                         // convert + store tile kt+1
            half8 av;
            if (rok) {
                if (AF32) {
                    av[0] = (_Float16)sv0.x; av[1] = (_Float16)sv0.y;
                    av[2] = (_Float16)sv0.z; av[3] = (_Float16)sv0.w;
                    av[4] = (_Float16)sv1.x; av[5] = (_Float16)sv1.y;
                    av[6] = (_Float16)sv1.z; av[7] = (_Float16)sv1.w;
                } else av = sh;
            } else {
#pragma unroll
                for (int i = 0; i < 8; ++i) av[i] = (_Float16)0.0f;
            }
            *(half8*)&Al[(kt + 1) & 1][arow * APAD + koff] = av;
        }
    }
    // epilogue: row = rb + wave*16 + g*4 + r, col = t*16 + fm
    const int rloc = wave * 16 + g * 4;
#pragma unroll
    for (int t = 0; t < NT; ++t) {
        int col = t * 16 + fm;
#pragma unroll
        for (int r = 0; r < 4; ++r) {
            int row = rb + rloc + r;
            if (row >= NN) continue;
            float v = acc[t][r];
            if (EPI == 0) {
                if (col < 128) lout[(size_t)row * 128 + col] = (f16)(v * dinv[row]);
                else           rout[(size_t)row * 128 + (col - 128)] = (f16)(v + bias[col - 128]);
            } else if (EPI == 1) {
                lout[(size_t)row * M + col] = (f16)(v * dinv[row]);
            } else if (EPI == 2) {
                lout[(size_t)row * M + col] = (f16)fmaxf(v + bias[col], 0.0f);
            } else {
                fout[(size_t)row * M + col] = v + bias[col];
            }
        }
    }
}

// ---------------- CSR gather + BN + ReLU (+residual) ----------------
template <bool RES>
__global__ __launch_bounds__(256) void k_gather(const int* __restrict__ rowptr,
                                                const int* __restrict__ csr,
                                                const float* __restrict__ dinv,
                                                const f16* __restrict__ lin,
                                                const f16* __restrict__ res,
                                                f16* __restrict__ h,
                                                const float* __restrict__ b,
                                                const float* __restrict__ g,
                                                const float* __restrict__ be) {
    const int gw = (blockIdx.x * 256 + threadIdx.x) >> 6;
    const int lane = threadIdx.x & 63;
    if (gw >= NN) return;
    const __half2* lp = (const __half2*)lin;
    const int start = rowptr[gw], end = rowptr[gw + 1];

    float2 acc = __half22float2(lp[(size_t)gw * 64 + lane]);  // self term
    int j = start;
    for (; j + 7 < end; j += 8) {
        int s0 = csr[j],     s1 = csr[j + 1], s2 = csr[j + 2], s3 = csr[j + 3];
        int s4 = csr[j + 4], s5 = csr[j + 5], s6 = csr[j + 6], s7 = csr[j + 7];
        float2 v0 = __half22float2(lp[(size_t)s0 * 64 + lane]);
        float2 v1 = __half22float2(lp[(size_t)s1 * 64 + lane]);
        float2 v2 = __half22float2(lp[(size_t)s2 * 64 + lane]);
        float2 v3 = __half22float2(lp[(size_t)s3 * 64 + lane]);
        float2 v4 = __half22float2(lp[(size_t)s4 * 64 + lane]);
        float2 v5 = __half22float2(lp[(size_t)s5 * 64 + lane]);
        float2 v6 = __half22float2(lp[(size_t)s6 * 64 + lane]);
        float2 v7 = __half22float2(lp[(size_t)s7 * 64 + lane]);
        acc.x += ((v0.x + v1.x) + (v2.x + v3.x)) + ((v4.x + v5.x) + (v6.x + v7.x));
        acc.y += ((v0.y + v1.y) + (v2.y + v3.y)) + ((v4.y + v5.y) + (v6.y + v7.y));
    }
    for (; j + 3 < end; j += 4) {
        int s0 = csr[j], s1 = csr[j + 1], s2 = csr[j + 2], s3 = csr[j + 3];
        float2 v0 = __half22float2(lp[(size_t)s0 * 64 + lane]);
        float2 v1 = __half22float2(lp[(size_t)s1 * 64 + lane]);
        float2 v2 = __half22float2(lp[(size_t)s2 * 64 + lane]);
        float2 v3 = __half22float2(lp[(size_t)s3 * 64 + lane]);
        acc.x += (v0.x + v1.x) + (v2.x + v3.x);
        acc.y += (v0.y + v1.y) + (v2.y + v3.y);
    }
    for (; j < end; ++j) {
        int s = csr[j];
        float2 v = __half22float2(lp[(size_t)s * 64 + lane]);
        acc.x += v.x;
        acc.y += v.y;
    }
    const float inv_sqrt = 0.99999500003749968f;  // 1/sqrt(1+1e-5)
    float dv = dinv[gw];
    int f = lane * 2;
    float2 bb = *(const float2*)&b[f];
    float2 gg = *(const float2*)&g[f];
    float2 ee = *(const float2*)&be[f];
    float t0 = fmaxf((acc.x * dv + bb.x) * (gg.x * inv_sqrt) + ee.x, 0.0f);
    float t1 = fmaxf((acc.y * dv + bb.y) * (gg.y * inv_sqrt) + ee.y, 0.0f);
    if (RES) {
        float2 rv = __half22float2(((const __half2*)res)[(size_t)gw * 64 + lane]);
        t0 += rv.x;
        t1 += rv.y;
    }
    ((__half2*)h)[(size_t)gw * 64 + lane] = __floats2half2_rn(t0, t1);
}

// ---------------- pooling ----------------
__global__ void k_count(const int* __restrict__ batch, float* __restrict__ cnt) {
    __shared__ float hist[NB];
    int tid = threadIdx.x;
    if (tid < NB) hist[tid] = 0.0f;
    __syncthreads();
    int n = blockIdx.x * 256 + tid;
    if (n < NN) atomicAdd(&hist[batch[n]], 1.0f);
    __syncthreads();
    if (tid < NB && hist[tid] != 0.0f) atomicAdd(&cnt[tid], hist[tid]);
}

__global__ void k_pool(const f16* __restrict__ h, const int* __restrict__ batch,
                       float* __restrict__ pool) {
    int n0 = blockIdx.x * 64;
    int j = threadIdx.x;
    int cur = batch[n0];
    float acc = 0.0f;
    int nend = (n0 + 64 < NN) ? n0 + 64 : NN;
    for (int n = n0; n < nend; ++n) {
        int b = batch[n];
        if (b != cur) {
            atomicAdd(&pool[cur * CH + j], acc);
            acc = 0.0f;
            cur = b;
        }
        acc += (float)h[(size_t)n * CH + j];
    }
    atomicAdd(&pool[cur * CH + j], acc);
}

__global__ void k_pool_fin(const float* __restrict__ pool,
                           const float* __restrict__ cnt,
                           float* __restrict__ out) {
    int i = blockIdx.x * 256 + threadIdx.x;
    if (i < NB * CH) {
        float c = fmaxf(cnt[i / CH], 1.0f);
        out[i] = pool[i] / c;
    }
}

// ---------------- launch ----------------
extern "C" void kernel_launch(void* const* d_in, const int* in_sizes, int n_in,
                              void* d_out, int out_size, void* d_ws, size_t ws_size,
                              hipStream_t stream) {
    float* outp  = (float*)d_out;                  // [NN, COUT] f32
    float* poolp = outp + (size_t)NN * COUT;       // [NB, CH] f32

    // ---- workspace layout (~84.2 MB; stage aliases rbuf) ----
    const size_t HB = (size_t)NN * CH * 2;
    const size_t LB = (size_t)NN * CH * 2;
    const size_t RB = (size_t)NN * CH * 2;
    const size_t DV = (size_t)NN * 4;
    const size_t RP = 400016;
    const size_t CS = (size_t)NE * 4;
    const size_t GC = 512;
    const size_t BA = 528;
    const size_t PL = (size_t)NB * CH * 4;
    const size_t CT = 256;
    const size_t F0B = 4096 * 16, F1B = 2048 * 16, FLB = 1024 * 16;
    const size_t need = HB + LB + RB + DV + RP + CS + GC + BA + PL + CT
                        + 2 * F0B + 3 * F1B + FLB;
    if (ws_size < need) {
        k_sentinel<<<(out_size + 255) / 256, 256, 0, stream>>>(outp, out_size, 2000.0f);
        return;
    }
    char* p = (char*)d_ws;
    f16*   hbuf   = (f16*)p;               p += HB;
    f16*   lbuf   = (f16*)p;               p += LB;
    f16*   rbuf   = (f16*)p;
    int*   stage  = (int*)p;               p += RB;   // alias: stage used before rbuf
    float* dinv   = (float*)p;             p += DV;
    int*   rowptr = (int*)p;               p += RP;
    int*   csr    = (int*)p;               p += CS;
    int*   gcur   = (int*)p;               p += GC;
    int*   barr   = (int*)p;               p += BA;
    float* pool   = (float*)p;             p += PL;
    float* cnt    = (float*)p;             p += CT;
    half8* F0     = (half8*)p;             p += F0B;
    half8* Fres   = (half8*)p;             p += F0B;
    half8* F1     = (half8*)p;             p += F1B;
    half8* F2     = (half8*)p;             p += F1B;
    half8* Fl0    = (half8*)p;             p += F1B;
    half8* Fl1    = (half8*)p;

    const float* x   = (const float*)d_in[0];
    const int*   ei  = (const int*)d_in[1];
    const int*   bat = (const int*)d_in[2];
    const float* W0 = (const float*)d_in[3],  *b0 = (const float*)d_in[4];
    const float* W1 = (const float*)d_in[5],  *b1 = (const float*)d_in[6];
    const float* W2 = (const float*)d_in[7],  *b2 = (const float*)d_in[8];
    const float* g0 = (const float*)d_in[9],  *be0 = (const float*)d_in[10];
    const float* g1 = (const float*)d_in[11], *be1 = (const float*)d_in[12];
    const float* g2 = (const float*)d_in[13], *be2 = (const float*)d_in[14];
    const float* Wres = (const float*)d_in[15], *bres = (const float*)d_in[16];
    const float* Wl0 = (const float*)d_in[17], *bl0 = (const float*)d_in[18];
    const float* Wl1 = (const float*)d_in[19], *bl1 = (const float*)d_in[20];

    const int* src = ei;
    const int* dst = ei + NE;

    const int gRow = (NN + 63) / 64;              // 1563
    const int gGat = (NN * 64) / 256;             // 25000

    // ---- CSR build ----
    k_init<<<33, 256, 0, stream>>>(pool, cnt, gcur);
    k_wconv<<<60, 256, 0, stream>>>(W0, Wres, W1, W2, Wl0, Wl1,
                                    F0, Fres, F1, F2, Fl0, Fl1);
    k_bin<<<G1, 256, 0, stream>>>(src, dst, gcur, stage);
    k_gtot<<<1, 64, 0, stream>>>(gcur, barr, rowptr);
    k_csr<<<NBUK, 256, 0, stream>>>(gcur, barr, stage, rowptr, csr, dinv);

    // ---- layer 0 fused with residual: one pass over x ----
    k_mfma<256, 0, true><<<gRow, 256, 0, stream>>>(x, F0, Fres, bres, dinv,
                                                   lbuf, rbuf, nullptr, CIN);
    k_gather<true><<<gGat, 256, 0, stream>>>(rowptr, csr, dinv, lbuf, rbuf, hbuf, b0, g0, be0);

    // ---- layer 1 ----
    k_mfma<128, 1, false><<<gRow, 256, 0, stream>>>(hbuf, F1, nullptr, nullptr, dinv,
                                                    lbuf, nullptr, nullptr, CH);
    k_gather<false><<<gGat, 256, 0, stream>>>(rowptr, csr, dinv, lbuf, nullptr, hbuf, b1, g1, be1);

    // ---- layer 2 ----
    k_mfma<128, 1, false><<<gRow, 256, 0, stream>>>(hbuf, F2, nullptr, nullptr, dinv,
                                                    lbuf, nullptr, nullptr, CH);
    k_gather<false><<<gGat, 256, 0, stream>>>(rowptr, csr, dinv, lbuf, nullptr, hbuf, b2, g2, be2);

    // ---- mean pool over graphs (final h) ----
    k_count<<<(NN + 255) / 256, 256, 0, stream>>>(bat, cnt);
    k_pool<<<gRow, 128, 0, stream>>>(hbuf, bat, pool);
    k_pool_fin<<<(NB * CH + 255) / 256, 256, 0, stream>>>(pool, cnt, poolp);

    // ---- head MLP ----
    k_mfma<128, 2, false><<<gRow, 256, 0, stream>>>(hbuf, Fl0, nullptr, bl0, nullptr,
                                                    lbuf, nullptr, nullptr, CH);
    k_mfma<64, 3, false><<<gRow, 256, 0, stream>>>(lbuf, Fl1, nullptr, bl1, nullptr,
                                                   nullptr, nullptr, outp, CH);
}

// Round 11
// 704.363 us; speedup vs baseline: 1.0583x; 1.0583x over previous
//
#include <hip/hip_runtime.h>
#include <hip/hip_fp16.h>

typedef __half f16;
typedef _Float16 half8 __attribute__((ext_vector_type(8)));
typedef float floatx4 __attribute__((ext_vector_type(4)));

#define NN   100000   // nodes
#define NE   1600000  // edges
#define CIN  256
#define CH   128
#define COUT 64
#define NB   64

#define NBUK 128      // CSR buckets
#define NPB  782      // nodes per bucket (128*782 = 100096 >= NN)
#define BCAP 32       // LDS bin slots per bucket (k_bin)
#define CAPB 20480    // staging capacity per bucket
#define G1   512      // k_bin blocks
#define EPB  3125     // edges per k_bin block
#define CSZ  15104    // k_csr LDS csr entries

// ---------------- diagnostics ----------------
__global__ void k_sentinel(float* __restrict__ out, int n, float val) {
    int i = blockIdx.x * 256 + threadIdx.x;
    if (i < n) out[i] = val;
}

// ---------------- init ----------------
__global__ void k_init(float* __restrict__ pool, float* __restrict__ cnt,
                       int* __restrict__ gcur) {
    int i = blockIdx.x * 256 + threadIdx.x;
    if (i < NB * CH) pool[i] = 0.0f;
    if (i < NB) cnt[i] = 0.0f;
    if (i < NBUK) gcur[i] = i * CAPB;
}

// ---------------- phase 1: bin edges by dst bucket ----------------
__global__ __launch_bounds__(256) void k_bin(const int* __restrict__ src,
                                             const int* __restrict__ dst,
                                             int* __restrict__ gcur,
                                             int* __restrict__ stage) {
    __shared__ int bins[NBUK][BCAP];
    __shared__ int bcnt[NBUK];
    __shared__ int fcnt[NBUK];
    __shared__ int fbase[NBUK];
    const int tid = threadIdx.x;
    if (tid < NBUK) bcnt[tid] = 0;
    __syncthreads();
    const int e0 = blockIdx.x * EPB;
    const int e1 = (e0 + EPB < NE) ? e0 + EPB : NE;
    for (int base = e0; base < e1; base += 256) {
        int e = base + tid;
        if (e < e1) {
            int s = src[e], d = dst[e];
            int bk = d / NPB;
            int pk = ((d - bk * NPB) << 17) | s;
            int pos = atomicAdd(&bcnt[bk], 1);
            if (pos < BCAP) {
                bins[bk][pos] = pk;
            } else {
                int gp = atomicAdd(&gcur[bk], 1);
                if (gp < (bk + 1) * CAPB) stage[gp] = pk;
            }
        }
        __syncthreads();
        if (tid < NBUK) {
            int stored = bcnt[tid]; if (stored > BCAP) stored = BCAP;
            int nf = stored & ~15;
            fcnt[tid] = nf;
            if (nf) fbase[tid] = atomicAdd(&gcur[tid], nf);
        }
        __syncthreads();
#pragma unroll
        for (int pass = 0; pass < NBUK / 16; ++pass) {
            int b = pass * 16 + (tid >> 4);
            int sl = tid & 15;
            int nf = fcnt[b];
            int fb = fbase[b];
            for (int k = sl; k < nf; k += 16)
                if (fb + k < (b + 1) * CAPB) stage[fb + k] = bins[b][k];
        }
        __syncthreads();
        if (tid < NBUK) {
            int stored = bcnt[tid]; if (stored > BCAP) stored = BCAP;
            int nf = fcnt[tid];
            for (int k = nf; k < stored; ++k) bins[tid][k - nf] = bins[tid][k];
            bcnt[tid] = stored - nf;
        }
        __syncthreads();
    }
    if (tid < NBUK) {
        int stored = bcnt[tid];
        fcnt[tid] = stored;
        if (stored) fbase[tid] = atomicAdd(&gcur[tid], stored);
    }
    __syncthreads();
#pragma unroll
    for (int pass = 0; pass < NBUK / 16; ++pass) {
        int b = pass * 16 + (tid >> 4);
        int sl = tid & 15;
        int nf = fcnt[b];
        int fb = fbase[b];
        for (int k = sl; k < nf; k += 16)
            if (fb + k < (b + 1) * CAPB) stage[fb + k] = bins[b][k];
    }
}

// ---------------- phase 1b: scan bucket totals ----------------
__global__ void k_gtot(const int* __restrict__ gcur, int* __restrict__ barr,
                       int* __restrict__ rowptr) {
    int lane = threadIdx.x;   // 64 threads
    int carry = 0;
    for (int c0 = 0; c0 < NBUK; c0 += 64) {
        int idx = c0 + lane;
        int orig = gcur[idx] - idx * CAPB;
        int v = orig;
#pragma unroll
        for (int off = 1; off < 64; off <<= 1) {
            int t = __shfl_up(v, off);
            if (lane >= off) v += t;
        }
        barr[idx] = v - orig + carry;
        carry += __shfl(v, 63);
    }
    if (lane == 0) rowptr[NN] = NE;
}

// ---------------- phase 2: per-bucket CSR + rowptr + dinv ----------------
__global__ __launch_bounds__(256) void k_csr(const int* __restrict__ gcur,
                                             const int* __restrict__ barr,
                                             const int* __restrict__ stage,
                                             int* __restrict__ rowptr,
                                             int* __restrict__ csr,
                                             float* __restrict__ dinv) {
    __shared__ int hist[NPB];
    __shared__ int lcsr[CSZ];
    const int b = blockIdx.x, tid = threadIdx.x;
    const int nbase = b * NPB;
    const int nloc = (NPB < NN - nbase) ? NPB : NN - nbase;
    const int count = gcur[b] - b * CAPB;
    const int gbase = barr[b];
    const int sb = b * CAPB;
    for (int i = tid; i < NPB; i += 256) hist[i] = 0;
    __syncthreads();
    for (int i = tid; i < count; i += 256)
        atomicAdd(&hist[stage[sb + i] >> 17], 1);
    __syncthreads();
    for (int dl = tid; dl < nloc; dl += 256)
        dinv[nbase + dl] = rsqrtf((float)hist[dl] + 1.0f);
    __syncthreads();
    if (tid < 64) {
        int carry = 0;
        for (int c0 = 0; c0 < NPB; c0 += 64) {
            int idx = c0 + tid;
            int orig = (idx < NPB) ? hist[idx] : 0;
            int v = orig;
#pragma unroll
            for (int off = 1; off < 64; off <<= 1) {
                int t = __shfl_up(v, off);
                if (tid >= off) v += t;
            }
            if (idx < NPB) hist[idx] = v - orig + carry;
            carry += __shfl(v, 63);
        }
    }
    __syncthreads();
    for (int dl = tid; dl < nloc; dl += 256)
        rowptr[nbase + dl] = gbase + hist[dl];
    __syncthreads();
    const bool fits = (count <= CSZ);
    for (int i = tid; i < count; i += 256) {
        int pk = stage[sb + i];
        int dl = pk >> 17, s = pk & 0x1FFFF;
        int pos = atomicAdd(&hist[dl], 1);
        if (fits) lcsr[pos] = s;
        else csr[gbase + pos] = s;
    }
    __syncthreads();
    if (fits)
        for (int i = tid; i < count; i += 256) csr[gbase + i] = lcsr[i];
}

// ---------------- weight -> f16 fragment-major conversion ----------------
__global__ __launch_bounds__(256) void k_wconv(
        const float* __restrict__ W0, const float* __restrict__ Wres,
        const float* __restrict__ W1, const float* __restrict__ W2,
        const float* __restrict__ Wl0, const float* __restrict__ Wl1,
        half8* __restrict__ F0, half8* __restrict__ Fres,
        half8* __restrict__ F1, half8* __restrict__ F2,
        half8* __restrict__ Fl0, half8* __restrict__ Fl1) {
    int f = blockIdx.x * 256 + threadIdx.x;
    const float* W; half8* F; int M, base;
    if      (f <  4096) { W = W0;   F = F0;   M = 128; base = 0; }
    else if (f <  8192) { W = Wres; F = Fres; M = 128; base = 4096; }
    else if (f < 10240) { W = W1;   F = F1;   M = 128; base = 8192; }
    else if (f < 12288) { W = W2;   F = F2;   M = 128; base = 10240; }
    else if (f < 14336) { W = Wl0;  F = Fl0;  M = 128; base = 12288; }
    else if (f < 15360) { W = Wl1;  F = Fl1;  M = 64;  base = 14336; }
    else return;
    int fl = f - base;
    int lane = fl & 63, fm = lane & 15, g = lane >> 4;
    int rest = fl >> 6;
    int nt = M / 16;
    int t = rest % nt, kt = rest / nt;
    half8 v;
#pragma unroll
    for (int j = 0; j < 8; ++j)
        v[j] = (_Float16)W[(size_t)(kt * 32 + g * 8 + j) * M + t * 16 + fm];
    F[fl] = v;
}

// ---------------- MFMA GEMM, barrier-free direct-fragment loads ----------
// C[N,M] = A[N,K] @ W[K,M]; 256 thr (4 waves), 64 rows x M cols per block.
// No LDS: each lane loads its A-fragment (rows have no cross-wave reuse) and
// its B-fragment (pre-converted, L2-resident) directly from global.
// A coalescing: 64 lanes = 16 rows x 32k contiguous (4 lanes per cache line).
template <int M, int K, int EPI, bool AF32>
__global__ __launch_bounds__(256) void k_mfma(const void* __restrict__ Av,
                                              const half8* __restrict__ WF,
                                              const half8* __restrict__ WFb,
                                              const float* __restrict__ bias,
                                              const float* __restrict__ dinv,
                                              f16* __restrict__ lout,
                                              f16* __restrict__ rout,
                                              float* __restrict__ fout) {
    constexpr int NT = M / 16;
    constexpr int KT = K / 32;
    const int tid = threadIdx.x;
    const int wave = tid >> 6, lane = tid & 63;
    const int fm = lane & 15, g = lane >> 4;
    const int rb = blockIdx.x * 64;
    const int arow = rb + wave * 16 + fm;      // this lane's A row
    const bool rok = (arow < NN);
    const size_t abase = rok ? (size_t)arow * K : 0;

    floatx4 acc[NT];
#pragma unroll
    for (int t = 0; t < NT; ++t)
#pragma unroll
        for (int r = 0; r < 4; ++r) acc[t][r] = 0.0f;

#pragma unroll 2
    for (int kt = 0; kt < KT; ++kt) {
        half8 af;
        if (rok) {
            if (AF32) {
                const float* ap = (const float*)Av + abase + kt * 32 + g * 8;
                float4 v0 = *(const float4*)ap;
                float4 v1 = *(const float4*)(ap + 4);
                af[0] = (_Float16)v0.x; af[1] = (_Float16)v0.y;
                af[2] = (_Float16)v0.z; af[3] = (_Float16)v0.w;
                af[4] = (_Float16)v1.x; af[5] = (_Float16)v1.y;
                af[6] = (_Float16)v1.z; af[7] = (_Float16)v1.w;
            } else {
                af = *(const half8*)((const _Float16*)Av + abase + kt * 32 + g * 8);
            }
        } else {
#pragma unroll
            for (int i = 0; i < 8; ++i) af[i] = (_Float16)0.0f;
        }
#pragma unroll
        for (int t = 0; t < NT; ++t) {
            half8 bf;
            if (EPI == 0) {
                bf = (t < 8) ? WF[((size_t)kt * 8 + t) * 64 + lane]
                             : WFb[((size_t)kt * 8 + (t - 8)) * 64 + lane];
            } else {
                bf = WF[((size_t)kt * NT + t) * 64 + lane];
            }
            acc[t] = __builtin_amdgcn_mfma_f32_16x16x32_f16(af, bf, acc[t], 0, 0, 0);
        }
    }
    // epilogue: row = rb + wave*16 + g*4 + r, col = t*16 + fm
    const int rloc = wave * 16 + g * 4;
#pragma unroll
    for (int t = 0; t < NT; ++t) {
        int col = t * 16 + fm;
#pragma unroll
        for (int r = 0; r < 4; ++r) {
            int row = rb + rloc + r;
            if (row >= NN) continue;
            float v = acc[t][r];
            if (EPI == 0) {
                if (col < 128) lout[(size_t)row * 128 + col] = (f16)(v * dinv[row]);
                else           rout[(size_t)row * 128 + (col - 128)] = (f16)(v + bias[col - 128]);
            } else if (EPI == 1) {
                lout[(size_t)row * M + col] = (f16)(v * dinv[row]);
            } else if (EPI == 2) {
                lout[(size_t)row * M + col] = (f16)fmaxf(v + bias[col], 0.0f);
            } else {
                fout[(size_t)row * M + col] = v + bias[col];
            }
        }
    }
}

// ---------------- CSR gather + BN + ReLU (+residual) ----------------
template <bool RES>
__global__ __launch_bounds__(256) void k_gather(const int* __restrict__ rowptr,
                                                const int* __restrict__ csr,
                                                const float* __restrict__ dinv,
                                                const f16* __restrict__ lin,
                                                const f16* __restrict__ res,
                                                f16* __restrict__ h,
                                                const float* __restrict__ b,
                                                const float* __restrict__ g,
                                                const float* __restrict__ be) {
    const int gw = (blockIdx.x * 256 + threadIdx.x) >> 6;
    const int lane = threadIdx.x & 63;
    if (gw >= NN) return;
    const __half2* lp = (const __half2*)lin;
    const int start = rowptr[gw], end = rowptr[gw + 1];

    float2 acc = __half22float2(lp[(size_t)gw * 64 + lane]);  // self term
    int j = start;
    for (; j + 7 < end; j += 8) {
        int s0 = csr[j],     s1 = csr[j + 1], s2 = csr[j + 2], s3 = csr[j + 3];
        int s4 = csr[j + 4], s5 = csr[j + 5], s6 = csr[j + 6], s7 = csr[j + 7];
        float2 v0 = __half22float2(lp[(size_t)s0 * 64 + lane]);
        float2 v1 = __half22float2(lp[(size_t)s1 * 64 + lane]);
        float2 v2 = __half22float2(lp[(size_t)s2 * 64 + lane]);
        float2 v3 = __half22float2(lp[(size_t)s3 * 64 + lane]);
        float2 v4 = __half22float2(lp[(size_t)s4 * 64 + lane]);
        float2 v5 = __half22float2(lp[(size_t)s5 * 64 + lane]);
        float2 v6 = __half22float2(lp[(size_t)s6 * 64 + lane]);
        float2 v7 = __half22float2(lp[(size_t)s7 * 64 + lane]);
        acc.x += ((v0.x + v1.x) + (v2.x + v3.x)) + ((v4.x + v5.x) + (v6.x + v7.x));
        acc.y += ((v0.y + v1.y) + (v2.y + v3.y)) + ((v4.y + v5.y) + (v6.y + v7.y));
    }
    for (; j + 3 < end; j += 4) {
        int s0 = csr[j], s1 = csr[j + 1], s2 = csr[j + 2], s3 = csr[j + 3];
        float2 v0 = __half22float2(lp[(size_t)s0 * 64 + lane]);
        float2 v1 = __half22float2(lp[(size_t)s1 * 64 + lane]);
        float2 v2 = __half22float2(lp[(size_t)s2 * 64 + lane]);
        float2 v3 = __half22float2(lp[(size_t)s3 * 64 + lane]);
        acc.x += (v0.x + v1.x) + (v2.x + v3.x);
        acc.y += (v0.y + v1.y) + (v2.y + v3.y);
    }
    for (; j < end; ++j) {
        int s = csr[j];
        float2 v = __half22float2(lp[(size_t)s * 64 + lane]);
        acc.x += v.x;
        acc.y += v.y;
    }
    const float inv_sqrt = 0.99999500003749968f;  // 1/sqrt(1+1e-5)
    float dv = dinv[gw];
    int f = lane * 2;
    float2 bb = *(const float2*)&b[f];
    float2 gg = *(const float2*)&g[f];
    float2 ee = *(const float2*)&be[f];
    float t0 = fmaxf((acc.x * dv + bb.x) * (gg.x * inv_sqrt) + ee.x, 0.0f);
    float t1 = fmaxf((acc.y * dv + bb.y) * (gg.y * inv_sqrt) + ee.y, 0.0f);
    if (RES) {
        float2 rv = __half22float2(((const __half2*)res)[(size_t)gw * 64 + lane]);
        t0 += rv.x;
        t1 += rv.y;
    }
    ((__half2*)h)[(size_t)gw * 64 + lane] = __floats2half2_rn(t0, t1);
}

// ---------------- pooling ----------------
__global__ void k_count(const int* __restrict__ batch, float* __restrict__ cnt) {
    __shared__ float hist[NB];
    int tid = threadIdx.x;
    if (tid < NB) hist[tid] = 0.0f;
    __syncthreads();
    int n = blockIdx.x * 256 + tid;
    if (n < NN) atomicAdd(&hist[batch[n]], 1.0f);
    __syncthreads();
    if (tid < NB && hist[tid] != 0.0f) atomicAdd(&cnt[tid], hist[tid]);
}

__global__ void k_pool(const f16* __restrict__ h, const int* __restrict__ batch,
                       float* __restrict__ pool) {
    int n0 = blockIdx.x * 64;
    int j = threadIdx.x;
    int cur = batch[n0];
    float acc = 0.0f;
    int nend = (n0 + 64 < NN) ? n0 + 64 : NN;
    for (int n = n0; n < nend; ++n) {
        int b = batch[n];
        if (b != cur) {
            atomicAdd(&pool[cur * CH + j], acc);
            acc = 0.0f;
            cur = b;
        }
        acc += (float)h[(size_t)n * CH + j];
    }
    atomicAdd(&pool[cur * CH + j], acc);
}

__global__ void k_pool_fin(const float* __restrict__ pool,
                           const float* __restrict__ cnt,
                           float* __restrict__ out) {
    int i = blockIdx.x * 256 + threadIdx.x;
    if (i < NB * CH) {
        float c = fmaxf(cnt[i / CH], 1.0f);
        out[i] = pool[i] / c;
    }
}

// ---------------- launch ----------------
extern "C" void kernel_launch(void* const* d_in, const int* in_sizes, int n_in,
                              void* d_out, int out_size, void* d_ws, size_t ws_size,
                              hipStream_t stream) {
    float* outp  = (float*)d_out;                  // [NN, COUT] f32
    float* poolp = outp + (size_t)NN * COUT;       // [NB, CH] f32

    // ---- workspace layout (~84.2 MB; stage aliases rbuf) ----
    const size_t HB = (size_t)NN * CH * 2;
    const size_t LB = (size_t)NN * CH * 2;
    const size_t RB = (size_t)NN * CH * 2;
    const size_t DV = (size_t)NN * 4;
    const size_t RP = 400016;
    const size_t CS = (size_t)NE * 4;
    const size_t GC = 512;
    const size_t BA = 528;
    const size_t PL = (size_t)NB * CH * 4;
    const size_t CT = 256;
    const size_t F0B = 4096 * 16, F1B = 2048 * 16, FLB = 1024 * 16;
    const size_t need = HB + LB + RB + DV + RP + CS + GC + BA + PL + CT
                        + 2 * F0B + 3 * F1B + FLB;
    if (ws_size < need) {
        k_sentinel<<<(out_size + 255) / 256, 256, 0, stream>>>(outp, out_size, 2000.0f);
        return;
    }
    char* p = (char*)d_ws;
    f16*   hbuf   = (f16*)p;               p += HB;
    f16*   lbuf   = (f16*)p;               p += LB;
    f16*   rbuf   = (f16*)p;
    int*   stage  = (int*)p;               p += RB;   // alias: stage used before rbuf
    float* dinv   = (float*)p;             p += DV;
    int*   rowptr = (int*)p;               p += RP;
    int*   csr    = (int*)p;               p += CS;
    int*   gcur   = (int*)p;               p += GC;
    int*   barr   = (int*)p;               p += BA;
    float* pool   = (float*)p;             p += PL;
    float* cnt    = (float*)p;             p += CT;
    half8* F0     = (half8*)p;             p += F0B;
    half8* Fres   = (half8*)p;             p += F0B;
    half8* F1     = (half8*)p;             p += F1B;
    half8* F2     = (half8*)p;             p += F1B;
    half8* Fl0    = (half8*)p;             p += F1B;
    half8* Fl1    = (half8*)p;

    const float* x   = (const float*)d_in[0];
    const int*   ei  = (const int*)d_in[1];
    const int*   bat = (const int*)d_in[2];
    const float* W0 = (const float*)d_in[3],  *b0 = (const float*)d_in[4];
    const float* W1 = (const float*)d_in[5],  *b1 = (const float*)d_in[6];
    const float* W2 = (const float*)d_in[7],  *b2 = (const float*)d_in[8];
    const float* g0 = (const float*)d_in[9],  *be0 = (const float*)d_in[10];
    const float* g1 = (const float*)d_in[11], *be1 = (const float*)d_in[12];
    const float* g2 = (const float*)d_in[13], *be2 = (const float*)d_in[14];
    const float* Wres = (const float*)d_in[15], *bres = (const float*)d_in[16];
    const float* Wl0 = (const float*)d_in[17], *bl0 = (const float*)d_in[18];
    const float* Wl1 = (const float*)d_in[19], *bl1 = (const float*)d_in[20];

    const int* src = ei;
    const int* dst = ei + NE;

    const int gRow = (NN + 63) / 64;              // 1563
    const int gGat = (NN * 64) / 256;             // 25000

    // ---- CSR build ----
    k_init<<<33, 256, 0, stream>>>(pool, cnt, gcur);
    k_wconv<<<60, 256, 0, stream>>>(W0, Wres, W1, W2, Wl0, Wl1,
                                    F0, Fres, F1, F2, Fl0, Fl1);
    k_bin<<<G1, 256, 0, stream>>>(src, dst, gcur, stage);
    k_gtot<<<1, 64, 0, stream>>>(gcur, barr, rowptr);
    k_csr<<<NBUK, 256, 0, stream>>>(gcur, barr, stage, rowptr, csr, dinv);

    // ---- layer 0 fused with residual: one pass over x ----
    k_mfma<256, 256, 0, true><<<gRow, 256, 0, stream>>>(x, F0, Fres, bres, dinv,
                                                        lbuf, rbuf, nullptr);
    k_gather<true><<<gGat, 256, 0, stream>>>(rowptr, csr, dinv, lbuf, rbuf, hbuf, b0, g0, be0);

    // ---- layer 1 ----
    k_mfma<128, 128, 1, false><<<gRow, 256, 0, stream>>>(hbuf, F1, nullptr, nullptr, dinv,
                                                         lbuf, nullptr, nullptr);
    k_gather<false><<<gGat, 256, 0, stream>>>(rowptr, csr, dinv, lbuf, nullptr, hbuf, b1, g1, be1);

    // ---- layer 2 ----
    k_mfma<128, 128, 1, false><<<gRow, 256, 0, stream>>>(hbuf, F2, nullptr, nullptr, dinv,
                                                         lbuf, nullptr, nullptr);
    k_gather<false><<<gGat, 256, 0, stream>>>(rowptr, csr, dinv, lbuf, nullptr, hbuf, b2, g2, be2);

    // ---- mean pool over graphs (final h) ----
    k_count<<<(NN + 255) / 256, 256, 0, stream>>>(bat, cnt);
    k_pool<<<gRow, 128, 0, stream>>>(hbuf, bat, pool);
    k_pool_fin<<<(NB * CH + 255) / 256, 256, 0, stream>>>(pool, cnt, poolp);

    // ---- head MLP ----
    k_mfma<128, 128, 2, false><<<gRow, 256, 0, stream>>>(hbuf, Fl0, nullptr, bl0, nullptr,
                                                         lbuf, nullptr, nullptr);
    k_mfma<64, 128, 3, false><<<gRow, 256, 0, stream>>>(lbuf, Fl1, nullptr, bl1, nullptr,
                                                        nullptr, nullptr, outp);
}